// Round 1
// baseline (605.950 us; speedup 1.0000x reference)
//
#include <hip/hip_runtime.h>
#include <cstdint>
#include <cstddef>

#define NN 4096
#define ITERS 50
#define TB 256            // tile is TB x TB
#define TSTRIDE 264       // halves per LDS tile row (16B-aligned rows)
#define NBLK 256          // 16 x 16 blocks
#define NTHR 1024

typedef _Float16 half4v __attribute__((ext_vector_type(4)));
typedef _Float16 half8v __attribute__((ext_vector_type(8)));

#define T_BYTES (TB * TSTRIDE * 2)                      // 135168
#define RED_FLOATS 4096                                 // red[16][256]
#define SMEM_BYTES (T_BYTES + RED_FLOATS * 4 + 1024 + 1024)   // 153600

#define SCOPE __HIP_MEMORY_SCOPE_AGENT

// ---------------------------------------------------------------------------
// Cooperative LDS-resident Sinkhorn with SINGLE-WORD fused exchange:
//   Each global row (and col) has one u64 accumulator per iteration slot.
//   Writer packs its positive fp32 partial into 20.32 fixed point plus an
//   arrival count in the top bits:  (1<<52) | (u64)(partial * 2^32)
//   and does a relaxed agent-scope atomicAdd (fire-and-forget, no drain, no
//   flag). Reader polls ONE 8B word until (v>>52)==16; the same load already
//   holds the exact fully-reduced sum (integer adds are associative/exact).
//   This removes per exchange: writer's vmcnt-drain-before-flag, the flag
//   store, the flag->data read, and the 16-way partial read+reduce.
// Range: max partial ~256*e at it=0 -> 16*700*2^32 < 2^46 << 2^52. Resolution
//   2^-32 absolute, far below the fp16 tile quantization error.
// Reuse: 4-deep rotation (it&3). After a block's poll of slot (it) completes,
//   it resets slot (it+2)&3 (last used it-2, next used it+2) and drains
//   vmcnt(0) before its next adds. Transitivity: my poll observing peer X's
//   iteration-it add implies X's it-2 poll finished (X program order), so no
//   reset hits a live reader; reset -> drain -> my next add -> >=3 LLC
//   observation hops before any it+2 add, so resets land before next use.
// ---------------------------------------------------------------------------

#define CNT_ONE (1ull << 52)
#define VAL_MASK (CNT_ONE - 1ull)

__global__ void sk_zero(unsigned long long* __restrict__ b) {
    size_t i = (size_t)blockIdx.x * blockDim.x + threadIdx.x;
    __hip_atomic_store(&b[i], 0ull, __ATOMIC_RELAXED, SCOPE);
}

__device__ __forceinline__ unsigned long long poll16(const unsigned long long* p) {
    unsigned long long v = __hip_atomic_load(p, __ATOMIC_RELAXED, SCOPE);
    while ((v >> 52) < 16ull) {
        __builtin_amdgcn_s_sleep(1);
        v = __hip_atomic_load(p, __ATOMIC_RELAXED, SCOPE);
    }
    return v;
}

__device__ __forceinline__ float unpack_recip(unsigned long long v) {
    return 1.0f / ((float)(v & VAL_MASK) * 0x1p-32f);
}

__device__ __forceinline__ unsigned long long packp(float s) {
    return CNT_ONE | (unsigned long long)(s * 4294967296.0f);
}

__global__ __launch_bounds__(NTHR) void sk_coop(const float* __restrict__ M,
                                                float* __restrict__ out,
                                                unsigned long long* __restrict__ rbuf,
                                                unsigned long long* __restrict__ cbuf) {
    extern __shared__ char smem[];
    _Float16* T   = (_Float16*)smem;               // [TB][TSTRIDE]
    float*    red = (float*)(smem + T_BYTES);      // [16][256]
    float*    rcv = red + RED_FLOATS;              // [256]
    float*    rrv = rcv + 256;                     // [256]

    const int t  = threadIdx.x;
    const int bi = blockIdx.x >> 4;    // row group
    const int bj = blockIdx.x & 15;    // col group
    const float* Mt = M + ((size_t)bi * TB) * NN + (size_t)bj * TB;

    // ---- load tile: E = exp(M) -> fp16 LDS ----
    #pragma unroll
    for (int i = 0; i < 16; ++i) {
        int idx = t + i * NTHR;
        int r = idx >> 6, c4 = idx & 63;
        float4 m = *(const float4*)(Mt + (size_t)r * NN + c4 * 4);
        half4v h;
        h[0] = (_Float16)__expf(m.x);
        h[1] = (_Float16)__expf(m.y);
        h[2] = (_Float16)__expf(m.z);
        h[3] = (_Float16)__expf(m.w);
        *(half4v*)&T[r * TSTRIDE + c4 * 4] = h;
    }

    for (int it = 0; it < ITERS; ++it) {
        unsigned long long* rb = rbuf + (size_t)(it & 3) * NN;
        unsigned long long* cb = cbuf + (size_t)(it & 3) * NN;

        // ---- stage 1: rcv from fused col accumulators of it-1 ----
        if (it == 0) {
            if (t < TB) {
                rcv[t] = 1.0f;
                // pre-reset slot used at it+1 (virgin; keeps protocol uniform)
                __hip_atomic_store(&cbuf[(size_t)1 * NN + (size_t)bj * TB + t],
                                   0ull, __ATOMIC_RELAXED, SCOPE);
            }
            __syncthreads();
        } else {
            if (t < TB) {
                unsigned long long v = poll16(
                    &cbuf[(size_t)((it - 1) & 3) * NN + (size_t)bj * TB + t]);
                rcv[t] = unpack_recip(v);
                // reset slot (it+1)&3 (last used it-3, readers done by it-2)
                __hip_atomic_store(&cbuf[(size_t)((it + 1) & 3) * NN
                                         + (size_t)bj * TB + t],
                                   0ull, __ATOMIC_RELAXED, SCOPE);
            }
            __syncthreads();
        }

        // ---- phase A: row sums. thread: row = t&255, q = t>>8 owns 64 cols ----
        {
            const int row = t & 255, q = t >> 8;
            const half8v* Trow = (const half8v*)&T[row * TSTRIDE + q * 64];
            const float4* rc4  = (const float4*)(rcv + q * 64);
            float s = 0.0f;
            #pragma unroll
            for (int k = 0; k < 8; ++k) {
                half8v hv = Trow[k];
                float4 c0 = rc4[2 * k];
                float4 c1 = rc4[2 * k + 1];
                s += (float)hv[0] * c0.x + (float)hv[1] * c0.y +
                     (float)hv[2] * c0.z + (float)hv[3] * c0.w +
                     (float)hv[4] * c1.x + (float)hv[5] * c1.y +
                     (float)hv[6] * c1.z + (float)hv[7] * c1.w;
            }
            red[q * 256 + row] = s;
        }
        __syncthreads();

        // ---- stage 2: fused row exchange (add -> poll same word) ----
        if (t < TB) {
            float s = red[t] + red[256 + t] + red[512 + t] + red[768 + t];
            unsigned long long pk = packp(s);
            // ensure stage-1 resets landed before this slot chain advances
            asm volatile("s_waitcnt vmcnt(0)" ::: "memory");
            unsigned long long* p = &rb[(size_t)bi * TB + t];
            __hip_atomic_fetch_add(p, pk, __ATOMIC_RELAXED, SCOPE);
            unsigned long long v = poll16(p);
            rrv[t] = unpack_recip(v);
            // reset rbuf slot (it+2)&3 (last used it-2; its readers are done)
            __hip_atomic_store(&rbuf[(size_t)((it + 2) & 3) * NN
                                     + (size_t)bi * TB + t],
                               0ull, __ATOMIC_RELAXED, SCOPE);
        }
        __syncthreads();

        // ---- phase B: col sums. ch = t&31 (8 cols), sub = t>>5 (8 rows) ----
        {
            const int ch = t & 31, sub = t >> 5;
            const int w = t >> 6, lane = t & 63;
            float acc[8] = {0, 0, 0, 0, 0, 0, 0, 0};
            #pragma unroll
            for (int r = 0; r < 8; ++r) {
                const int row = sub * 8 + r;
                half8v hv = *(const half8v*)&T[row * TSTRIDE + ch * 8];
                float rr = rrv[row];
                #pragma unroll
                for (int j = 0; j < 8; ++j) acc[j] += (float)hv[j] * rr;
            }
            #pragma unroll
            for (int j = 0; j < 8; ++j) acc[j] += __shfl_down(acc[j], 32);
            if (lane < 32) {
                const int rot = (lane >> 2) & 7;
                float* rd = red + w * 256 + ch * 8;
                #pragma unroll
                for (int jj = 0; jj < 8; ++jj) {
                    int j = (jj + rot) & 7;
                    rd[j] = acc[j];
                }
            }
        }
        __syncthreads();

        // ---- stage 3: fused col exchange (add only; polled next iteration) ----
        if (t < TB) {
            float s = 0.0f;
            #pragma unroll
            for (int w = 0; w < 16; ++w) s += red[w * 256 + t];
            unsigned long long pk = packp(s);
            // ensure stage-2 resets landed before this slot chain advances
            asm volatile("s_waitcnt vmcnt(0)" ::: "memory");
            __hip_atomic_fetch_add(&cb[(size_t)bj * TB + t], pk,
                                   __ATOMIC_RELAXED, SCOPE);
        }
        // no barrier needed: stage-1 barrier of next iteration orders
        // stage-3 red reads against the next phase-A red writes.
    }

    // ---- epilogue: poll final col accumulators; out = max(exp(M)*rr*rc, 1e-9) ----
    if (t < TB) {
        unsigned long long v = poll16(
            &cbuf[(size_t)((ITERS - 1) & 3) * NN + (size_t)bj * TB + t]);
        rcv[t] = unpack_recip(v);
    }
    __syncthreads();

    float* outt = out + ((size_t)bi * TB) * NN + (size_t)bj * TB;
    #pragma unroll
    for (int i = 0; i < 16; ++i) {
        int idx = t + i * NTHR;
        int r = idx >> 6, c4 = idx & 63;
        float4 m = *(const float4*)(Mt + (size_t)r * NN + c4 * 4);
        float rr = rrv[r];
        float4 c = ((const float4*)rcv)[c4];
        float4 o;
        o.x = fmaxf(__expf(m.x) * rr * c.x, 1e-9f);
        o.y = fmaxf(__expf(m.y) * rr * c.y, 1e-9f);
        o.z = fmaxf(__expf(m.z) * rr * c.z, 1e-9f);
        o.w = fmaxf(__expf(m.w) * rr * c.w, 1e-9f);
        *(float4*)(outt + (size_t)r * NN + c4 * 4) = o;
    }
}

// ===========================================================================
// Fallback multi-kernel path (round-1, known-good).
// ===========================================================================

__global__ __launch_bounds__(256) void sk_init(float* __restrict__ rc,
                                               float* __restrict__ c_sum) {
    int j = blockIdx.x * 256 + threadIdx.x;
    rc[j] = 1.0f;
    c_sum[j] = 0.0f;
}

__global__ __launch_bounds__(256) void sk_exp(const float* __restrict__ M,
                                              float* __restrict__ E) {
    size_t idx = ((size_t)blockIdx.x * 256 + threadIdx.x) * 4;
    float4 m = *(const float4*)(M + idx);
    float4 e;
    e.x = __expf(m.x); e.y = __expf(m.y); e.z = __expf(m.z); e.w = __expf(m.w);
    *(float4*)(E + idx) = e;
}

template<bool HAS_E>
__global__ __launch_bounds__(256) void sk_row(const float* __restrict__ Mat,
                                              const float* __restrict__ rc,
                                              float* __restrict__ rr) {
    const int wave = threadIdx.x >> 6;
    const int lane = threadIdx.x & 63;
    const int row  = blockIdx.x * 4 + wave;
    const float4* __restrict__ Mrow = (const float4*)(Mat + (size_t)row * NN);
    const float4* __restrict__ RC   = (const float4*)rc;
    float s = 0.0f;
    #pragma unroll 4
    for (int k = lane; k < NN / 4; k += 64) {
        float4 m = Mrow[k];
        float4 c = RC[k];
        if (!HAS_E) {
            m.x = __expf(m.x); m.y = __expf(m.y);
            m.z = __expf(m.z); m.w = __expf(m.w);
        }
        s += m.x * c.x + m.y * c.y + m.z * c.z + m.w * c.w;
    }
    #pragma unroll
    for (int off = 32; off > 0; off >>= 1) s += __shfl_down(s, off, 64);
    if (lane == 0) rr[row] = 1.0f / s;
}

template<bool HAS_E>
__global__ __launch_bounds__(256) void sk_col(const float* __restrict__ Mat,
                                              const float* __restrict__ rr,
                                              float* __restrict__ c_sum) {
    const int j  = blockIdx.x * 256 + threadIdx.x;
    const int r0 = blockIdx.y * 64;
    const float* __restrict__ rrp = rr + r0;
    const float* __restrict__ p   = Mat + (size_t)r0 * NN + j;
    float s = 0.0f;
    #pragma unroll 8
    for (int i = 0; i < 64; ++i) {
        float m = p[(size_t)i * NN];
        if (!HAS_E) m = __expf(m);
        s += m * rrp[i];
    }
    atomicAdd(&c_sum[j], s);
}

__global__ __launch_bounds__(256) void sk_recip(float* __restrict__ c_sum,
                                                float* __restrict__ rc) {
    int j = blockIdx.x * 256 + threadIdx.x;
    rc[j] = 1.0f / c_sum[j];
    c_sum[j] = 0.0f;
}

template<bool HAS_E>
__global__ __launch_bounds__(256) void sk_final(const float* __restrict__ Mat,
                                                const float* __restrict__ rr,
                                                const float* __restrict__ rc,
                                                float* __restrict__ out) {
    const int row = blockIdx.y;
    const int c4  = blockIdx.x * 256 + threadIdx.x;
    float4 m = ((const float4*)(Mat + (size_t)row * NN))[c4];
    if (!HAS_E) {
        m.x = __expf(m.x); m.y = __expf(m.y);
        m.z = __expf(m.z); m.w = __expf(m.w);
    }
    float4 c = ((const float4*)rc)[c4];
    float  r = rr[row];
    float4 o;
    o.x = fmaxf(m.x * r * c.x, 1e-9f);
    o.y = fmaxf(m.y * r * c.y, 1e-9f);
    o.z = fmaxf(m.z * r * c.z, 1e-9f);
    o.w = fmaxf(m.w * r * c.w, 1e-9f);
    ((float4*)out)[(size_t)row * (NN / 4) + c4] = o;
}

static void launch_fallback(const float* M, float* out, char* ws, size_t ws_size,
                            hipStream_t stream) {
    float* rc    = (float*)(ws);
    float* rr    = (float*)(ws + 16 * 1024);
    float* c_sum = (float*)(ws + 32 * 1024);
    float* E     = (float*)(ws + 64 * 1024);

    const size_t need_e = 64 * 1024 + (size_t)NN * NN * sizeof(float);
    const bool   has_e  = ws_size >= need_e;

    sk_init<<<NN / 256, 256, 0, stream>>>(rc, c_sum);

    const float* Mat = M;
    if (has_e) {
        sk_exp<<<(NN * (size_t)NN) / 1024, 256, 0, stream>>>(M, E);
        Mat = E;
    }

    dim3 gcol(16, 64);
    for (int it = 0; it < ITERS; ++it) {
        if (has_e) sk_row<true ><<<NN / 4, 256, 0, stream>>>(Mat, rc, rr);
        else       sk_row<false><<<NN / 4, 256, 0, stream>>>(Mat, rc, rr);
        if (has_e) sk_col<true ><<<gcol, 256, 0, stream>>>(Mat, rr, c_sum);
        else       sk_col<false><<<gcol, 256, 0, stream>>>(Mat, rr, c_sum);
        sk_recip<<<NN / 256, 256, 0, stream>>>(c_sum, rc);
    }

    dim3 gfin(4, NN);
    if (has_e) sk_final<true ><<<gfin, 256, 0, stream>>>(Mat, rr, rc, out);
    else       sk_final<false><<<gfin, 256, 0, stream>>>(Mat, rr, rc, out);
}

extern "C" void kernel_launch(void* const* d_in, const int* in_sizes, int n_in,
                              void* d_out, int out_size, void* d_ws, size_t ws_size,
                              hipStream_t stream) {
    const float* M   = (const float*)d_in[0];
    float*       out = (float*)d_out;
    char*        ws  = (char*)d_ws;

    // coop-path workspace: rbuf[4][NN] u64 | cbuf[4][NN] u64  (256 KiB)
    unsigned long long* rbuf = (unsigned long long*)ws;
    unsigned long long* cbuf = rbuf + 4 * NN;
    const size_t ws_need = (size_t)8 * NN * sizeof(unsigned long long);

    int dev = 0;
    (void)hipGetDevice(&dev);
    int coop = 0;
    (void)hipDeviceGetAttribute(&coop, hipDeviceAttributeCooperativeLaunch, dev);
    hipError_t eattr = hipFuncSetAttribute(
        (const void*)sk_coop, hipFuncAttributeMaxDynamicSharedMemorySize, SMEM_BYTES);

    bool done = false;
    if (coop && eattr == hipSuccess && ws_size >= ws_need) {
        sk_zero<<<16, 512, 0, stream>>>(rbuf);   // zero both buffers (8192 u64)
        void* args[4] = {(void*)&M, (void*)&out, (void*)&rbuf, (void*)&cbuf};
        hipError_t e = hipLaunchCooperativeKernel((void*)sk_coop, dim3(NBLK),
                                                  dim3(NTHR), args, SMEM_BYTES,
                                                  stream);
        done = (e == hipSuccess);
    }
    if (!done) launch_fallback(M, out, ws, ws_size, stream);
}